// Round 1
// baseline (193.142 us; speedup 1.0000x reference)
//
#include <hip/hip_runtime.h>
#include <math.h>

// BinarySphericalQuantizer forward, EMBED_DIM=16, all scalars = 1.
// Outputs concatenated in d_out (float32):
//   [0, n)                : zq = sign(z)*0.25            (n = 33554432)
//   [n]                   : loss = persample_entropy - cb_entropy
//   [n+1, n+1+rows)       : indices (bit-packed signs), as float
//   [n+1+rows, +32)       : avg_prob (16 x 2)
//
// Derivations: with INV_T=1, s = z/||z|| (per 16-elem row, norm clamped at 1e-12),
//   p        = sigmoid(-s) = 1/(1+e^s)
//   H(p,1-p) = ln(1+e^s) - s*(1-p)          (eps=1e-8 inside ref log ~ 2e-8/elem, negligible)
//   avg_prob[g] = (mean_p[g], 1-mean_p[g])

__global__ __launch_bounds__(256) void bsq_main(
    const float* __restrict__ z,
    float* __restrict__ zq,
    float* __restrict__ idx_out,
    float* __restrict__ ws_h,      // [gridDim.x] float partials of entropy sum
    float* __restrict__ ws_p,      // [16][gridDim.x] float partials of p-sums
    long long quads)               // n/4
{
    const int tid = threadIdx.x;
    const long long stride = (long long)gridDim.x * blockDim.x;
    long long q = (long long)blockIdx.x * blockDim.x + tid;

    const int c = tid & 3;         // quad position within row (stride % 4 == 0)

    float h_acc = 0.f;
    float p_acc[4] = {0.f, 0.f, 0.f, 0.f};

    for (; q < quads; q += stride) {
        const float4 v = reinterpret_cast<const float4*>(z)[q];
        float vv[4] = {v.x, v.y, v.z, v.w};

        float ss = v.x*v.x + v.y*v.y + v.z*v.z + v.w*v.w;
        ss += __shfl_xor(ss, 1);   // lanes 4m..4m+3 hold one row
        ss += __shfl_xor(ss, 2);
        // ref: z / max(sqrt(ss), 1e-12)  ==  z * rsqrt(max(ss, 1e-24))
        const float scale = rsqrtf(fmaxf(ss, 1e-24f));

        unsigned bits = 0u;
        float4 o;
        float* op = &o.x;
        #pragma unroll
        for (int j = 0; j < 4; ++j) {
            const float s   = vv[j] * scale;
            const float e   = __expf(s);
            const float inv = 1.0f / (1.0f + e);       // p = sigmoid(-s)
            const float h   = __logf(1.0f + e) - s * (1.0f - inv);
            h_acc    += h;
            p_acc[j] += inv;
            const bool bit = vv[j] > 0.0f;
            op[j] = bit ? 0.25f : -0.25f;
            bits |= (bit ? 1u : 0u) << (15 - (4 * c + j));
        }
        reinterpret_cast<float4*>(zq)[q] = o;

        bits |= __shfl_xor(bits, 1);
        bits |= __shfl_xor(bits, 2);
        if (c == 0) idx_out[q >> 2] = (float)bits;     // fits exactly in f32 (<= 65535)
    }

    // wave reduce: h over all 64 lanes; p over the 16 lanes sharing (lane&3)
    #pragma unroll
    for (int m = 32; m >= 4; m >>= 1) {
        h_acc += __shfl_xor(h_acc, m);
        #pragma unroll
        for (int j = 0; j < 4; ++j) p_acc[j] += __shfl_xor(p_acc[j], m);
    }
    h_acc += __shfl_xor(h_acc, 2);
    h_acc += __shfl_xor(h_acc, 1);

    __shared__ float sh_h[4];
    __shared__ float sh_p[4][16];
    const int wave = tid >> 6;
    const int lane = tid & 63;
    if (lane == 0) sh_h[wave] = h_acc;
    if (lane < 4) {
        #pragma unroll
        for (int j = 0; j < 4; ++j) sh_p[wave][4 * lane + j] = p_acc[j];
    }
    __syncthreads();

    if (tid == 0)
        ws_h[blockIdx.x] = sh_h[0] + sh_h[1] + sh_h[2] + sh_h[3];
    if (tid < 16)
        ws_p[(long long)tid * gridDim.x + blockIdx.x] =
            sh_p[0][tid] + sh_p[1][tid] + sh_p[2][tid] + sh_p[3][tid];
}

__global__ __launch_bounds__(64) void bsq_final(
    const float* __restrict__ ws_h,
    const float* __restrict__ ws_p,
    float* __restrict__ loss_out,
    float* __restrict__ avgp_out,
    int nb, long long rows)
{
    const int lane = threadIdx.x;
    const double invR = 1.0 / (double)rows;

    double h = 0.0;
    for (int i = lane; i < nb; i += 64) h += (double)ws_h[i];
    #pragma unroll
    for (int m = 32; m >= 1; m >>= 1) h += __shfl_xor(h, m);
    const double persample = h * invR;

    double cb = 0.0;
    double qv[16];
    for (int g = 0; g < 16; ++g) {
        double p = 0.0;
        for (int i = lane; i < nb; i += 64) p += (double)ws_p[(long long)g * nb + i];
        #pragma unroll
        for (int m = 32; m >= 1; m >>= 1) p += __shfl_xor(p, m);
        const double qq = p * invR;
        qv[g] = qq;
        cb += -(qq * log(qq + 1e-8) + (1.0 - qq) * log((1.0 - qq) + 1e-8));
    }

    if (lane == 0) {
        loss_out[0] = (float)(persample - cb);   // GAMMA0=GAMMA=ZETA=INV_T=1
        for (int g = 0; g < 16; ++g) {
            avgp_out[2 * g]     = (float)qv[g];
            avgp_out[2 * g + 1] = (float)(1.0 - qv[g]);
        }
    }
}

extern "C" void kernel_launch(void* const* d_in, const int* in_sizes, int n_in,
                              void* d_out, int out_size, void* d_ws, size_t ws_size,
                              hipStream_t stream) {
    const float* z = (const float*)d_in[0];
    const long long n    = in_sizes[0];     // 33554432
    const long long rows = n / 16;          // 2097152
    const long long quads = n / 4;          // 8388608

    float* out   = (float*)d_out;
    float* zq    = out;
    float* loss  = out + n;
    float* idx   = out + n + 1;
    float* avgp  = out + n + 1 + rows;

    const int NB = 2048;
    float* ws_h = (float*)d_ws;             // NB floats
    float* ws_p = ws_h + NB;                // 16*NB floats (total ~139 KB << ws_size)

    bsq_main<<<NB, 256, 0, stream>>>(z, zq, idx, ws_h, ws_p, quads);
    bsq_final<<<1, 64, 0, stream>>>(ws_h, ws_p, loss, avgp, NB, rows);
}

// Round 2
// 74.712 us; speedup vs baseline: 2.5851x; 2.5851x over previous
//
#include <hip/hip_runtime.h>
#include <math.h>

// BinarySphericalQuantizer forward, EMBED_DIM=16, all scalars = 1.
// Outputs concatenated in d_out (float32):
//   [0, n)                : zq = sign(z)*0.25            (n = 33554432)
//   [n]                   : loss = persample_entropy - cb_entropy
//   [n+1, n+1+rows)       : indices (bit-packed signs), as float
//   [n+1+rows, +32)       : avg_prob (16 x 2)
//
// Derivations: with INV_T=1, s = z/||z|| (per 16-elem row, norm clamped at 1e-12),
//   p        = sigmoid(-s) = 1/(1+e^s)
//   H(p,1-p) = ln(1+e^s) - s*(1-p)          (eps=1e-8 inside ref log ~ 2e-8/elem, negligible)
//   avg_prob[g] = (mean_p[g], 1-mean_p[g])

__global__ __launch_bounds__(256) void bsq_main(
    const float* __restrict__ z,
    float* __restrict__ zq,
    float* __restrict__ idx_out,
    float* __restrict__ ws_h,      // [gridDim.x] float partials of entropy sum
    float* __restrict__ ws_p,      // [16][gridDim.x] float partials of p-sums
    long long quads)               // n/4
{
    const int tid = threadIdx.x;
    const long long stride = (long long)gridDim.x * blockDim.x;
    long long q = (long long)blockIdx.x * blockDim.x + tid;

    const int c = tid & 3;         // quad position within row (stride % 4 == 0)

    float h_acc = 0.f;
    float p_acc[4] = {0.f, 0.f, 0.f, 0.f};

    for (; q < quads; q += stride) {
        const float4 v = reinterpret_cast<const float4*>(z)[q];
        float vv[4] = {v.x, v.y, v.z, v.w};

        float ss = v.x*v.x + v.y*v.y + v.z*v.z + v.w*v.w;
        ss += __shfl_xor(ss, 1);   // lanes 4m..4m+3 hold one row
        ss += __shfl_xor(ss, 2);
        // ref: z / max(sqrt(ss), 1e-12)  ==  z * rsqrt(max(ss, 1e-24))
        const float scale = rsqrtf(fmaxf(ss, 1e-24f));

        unsigned bits = 0u;
        float4 o;
        float* op = &o.x;
        #pragma unroll
        for (int j = 0; j < 4; ++j) {
            const float s   = vv[j] * scale;
            const float e   = __expf(s);
            const float inv = 1.0f / (1.0f + e);       // p = sigmoid(-s)
            const float h   = __logf(1.0f + e) - s * (1.0f - inv);
            h_acc    += h;
            p_acc[j] += inv;
            const bool bit = vv[j] > 0.0f;
            op[j] = bit ? 0.25f : -0.25f;
            bits |= (bit ? 1u : 0u) << (15 - (4 * c + j));
        }
        reinterpret_cast<float4*>(zq)[q] = o;

        bits |= __shfl_xor(bits, 1);
        bits |= __shfl_xor(bits, 2);
        if (c == 0) idx_out[q >> 2] = (float)bits;     // fits exactly in f32 (<= 65535)
    }

    // wave reduce: h over all 64 lanes; p over the 16 lanes sharing (lane&3)
    #pragma unroll
    for (int m = 32; m >= 4; m >>= 1) {
        h_acc += __shfl_xor(h_acc, m);
        #pragma unroll
        for (int j = 0; j < 4; ++j) p_acc[j] += __shfl_xor(p_acc[j], m);
    }
    h_acc += __shfl_xor(h_acc, 2);
    h_acc += __shfl_xor(h_acc, 1);

    __shared__ float sh_h[4];
    __shared__ float sh_p[4][16];
    const int wave = tid >> 6;
    const int lane = tid & 63;
    if (lane == 0) sh_h[wave] = h_acc;
    if (lane < 4) {
        #pragma unroll
        for (int j = 0; j < 4; ++j) sh_p[wave][4 * lane + j] = p_acc[j];
    }
    __syncthreads();

    if (tid == 0)
        ws_h[blockIdx.x] = sh_h[0] + sh_h[1] + sh_h[2] + sh_h[3];
    if (tid < 16)
        ws_p[(long long)tid * gridDim.x + blockIdx.x] =
            sh_p[0][tid] + sh_p[1][tid] + sh_p[2][tid] + sh_p[3][tid];
}

// 16 waves: wave w reduces p-group w; wave 0 also reduces h. All loads for a
// lane are independent -> single vmcnt wait, ~1-2 us instead of 139 us for the
// old single-wave serial version.
__global__ __launch_bounds__(1024) void bsq_final(
    const float* __restrict__ ws_h,
    const float* __restrict__ ws_p,
    float* __restrict__ loss_out,
    float* __restrict__ avgp_out,
    int nb, long long rows)
{
    const int tid  = threadIdx.x;
    const int wave = tid >> 6;     // 0..15
    const int lane = tid & 63;
    const double invR = 1.0 / (double)rows;

    __shared__ double sh_q[16];
    __shared__ double sh_h;

    double p = 0.0;
    for (int i = lane; i < nb; i += 64)
        p += (double)ws_p[(long long)wave * nb + i];

    double h = 0.0;
    if (wave == 0)
        for (int i = lane; i < nb; i += 64)
            h += (double)ws_h[i];

    #pragma unroll
    for (int m = 32; m >= 1; m >>= 1)
        p += __shfl_xor(p, m);
    if (wave == 0) {
        #pragma unroll
        for (int m = 32; m >= 1; m >>= 1)
            h += __shfl_xor(h, m);
        if (lane == 0) sh_h = h * invR;
    }
    if (lane == 0) sh_q[wave] = p * invR;
    __syncthreads();

    if (wave == 0) {
        const double q = (lane < 16) ? sh_q[lane] : 0.0;
        double term = 0.0;
        if (lane < 16)
            term = -(q * log(q + 1e-8) + (1.0 - q) * log((1.0 - q) + 1e-8));
        #pragma unroll
        for (int m = 32; m >= 1; m >>= 1)
            term += __shfl_xor(term, m);
        if (lane == 0)
            loss_out[0] = (float)(sh_h - term);   // GAMMA0=GAMMA=ZETA=INV_T=1
        if (lane < 16) {
            avgp_out[2 * lane]     = (float)sh_q[lane];
            avgp_out[2 * lane + 1] = (float)(1.0 - sh_q[lane]);
        }
    }
}

extern "C" void kernel_launch(void* const* d_in, const int* in_sizes, int n_in,
                              void* d_out, int out_size, void* d_ws, size_t ws_size,
                              hipStream_t stream) {
    const float* z = (const float*)d_in[0];
    const long long n    = in_sizes[0];     // 33554432
    const long long rows = n / 16;          // 2097152
    const long long quads = n / 4;          // 8388608

    float* out   = (float*)d_out;
    float* zq    = out;
    float* loss  = out + n;
    float* idx   = out + n + 1;
    float* avgp  = out + n + 1 + rows;

    const int NB = 2048;
    float* ws_h = (float*)d_ws;             // NB floats
    float* ws_p = ws_h + NB;                // 16*NB floats (total ~139 KB << ws_size)

    bsq_main<<<NB, 256, 0, stream>>>(z, zq, idx, ws_h, ws_p, quads);
    bsq_final<<<1, 1024, 0, stream>>>(ws_h, ws_p, loss, avgp, NB, rows);
}